// Round 1
// 550.596 us; speedup vs baseline: 1.0776x; 1.0776x over previous
//
#include <hip/hip_runtime.h>
#include <hip/hip_bf16.h>

// Problem constants
#define NN   20000          // nodes
#define DIN_ 92             // atom feature dim
#define CC   128            // hidden dim
#define EE   640000         // edges (self loops handled explicitly)
#define BN_EPS 1e-5f
#define NEG_INF (-3.0e38f)

typedef short short8 __attribute__((ext_vector_type(8)));
typedef float floatx4 __attribute__((ext_vector_type(4)));

// ---------------------------------------------------------------------------
// Dual-dtype helpers: flags[0]=1 -> external floats are fp32 (else bf16)
//                     flags[1]=1 -> edge_index is int64 (else int32)
// ---------------------------------------------------------------------------
static __device__ __forceinline__ float b2f(__hip_bfloat16 v) { return __bfloat162float(v); }
static __device__ __forceinline__ float ldf(const void* p, int i, int f32) {
    return f32 ? ((const float*)p)[i]
               : __bfloat162float(((const __hip_bfloat16*)p)[i]);
}
static __device__ __forceinline__ void stf(void* p, int i, float v, int f32) {
    if (f32) ((float*)p)[i] = v;
    else     ((__hip_bfloat16*)p)[i] = __float2bfloat16(v);
}
static __device__ __forceinline__ float leaky02(float x) { return x > 0.f ? x : 0.2f * x; }

// bf16 decode via bit ops (bf16 = top half of fp32)
static __device__ __forceinline__ float2 bfp(unsigned w) {
    return make_float2(__uint_as_float(w << 16), __uint_as_float(w & 0xffff0000u));
}
static __device__ __forceinline__ float4 bf4(unsigned x, unsigned y) {
    return make_float4(__uint_as_float(x << 16), __uint_as_float(x & 0xffff0000u),
                       __uint_as_float(y << 16), __uint_as_float(y & 0xffff0000u));
}
static __device__ __forceinline__ uint2 f4bf(float4 v) {
    union { uint2 u; __hip_bfloat16 b[4]; } x;
    x.b[0] = __float2bfloat16(v.x); x.b[1] = __float2bfloat16(v.y);
    x.b[2] = __float2bfloat16(v.z); x.b[3] = __float2bfloat16(v.w);
    return x.u;
}
static __device__ __forceinline__ unsigned f2bf(float2 v) {
    union { unsigned u; __hip_bfloat16 b[2]; } x;
    x.b[0] = __float2bfloat16(v.x); x.b[1] = __float2bfloat16(v.y);
    return x.u;
}

// ---------------------------------------------------------------------------
// Runtime dtype detection
// ---------------------------------------------------------------------------
__global__ void detect_kernel(const unsigned int* __restrict__ x0,
                              const unsigned int* __restrict__ ei,
                              int* __restrict__ flags)
{
    __shared__ int cnt_band, cnt_zero;
    if (threadIdx.x == 0) { cnt_band = 0; cnt_zero = 0; }
    __syncthreads();
    unsigned w  = x0[threadIdx.x];
    unsigned eb = ((w & 0xFFFFu) >> 7) & 0xFFu;
    if (eb >= 90u && eb <= 140u) atomicAdd(&cnt_band, 1);
    if (ei[2 * threadIdx.x + 1] == 0u) atomicAdd(&cnt_zero, 1);
    __syncthreads();
    if (threadIdx.x == 0) {
        flags[0] = (cnt_band < 200) ? 1 : 0;   // 1 = fp32
        flags[1] = (cnt_zero >= 250) ? 1 : 0;  // 1 = int64
    }
}

// ---------------------------------------------------------------------------
// Merged conversion: transposed bf16 weights + padded bf16 node features
// ---------------------------------------------------------------------------
#define R0_ 12288
#define R1_ (R0_ + 16384)
#define R2_ (R1_ + 16384)
#define R3_ (R2_ + 16384)
#define R4_ (R3_ + 16384)
#define R5_ (R4_ + 32768)
#define R6_ (R5_ + 32768)          // 143360 weight elements
#define TCVT (R6_ + NN * 96)       // + node features

__global__ void cvt_all_kernel(const void* __restrict__ w_emb, const void* __restrict__ w1,
                               const void* __restrict__ w2, const void* __restrict__ wmu,
                               const void* __restrict__ wvar, const void* __restrict__ wgat,
                               const void* __restrict__ wdec, const void* __restrict__ xin,
                               __hip_bfloat16* __restrict__ dst, const int* __restrict__ flags)
{
    const int f32 = flags[0];
    int i = blockIdx.x * blockDim.x + threadIdx.x;
    if (i >= TCVT) return;
    float v;
    if (i < R0_) {
        int n = i / 96, k = i - n * 96;
        v = (k < DIN_) ? ldf(w_emb, k * 128 + n, f32) : 0.f;
    } else if (i < R1_) {
        int j = i - R0_; int n = j >> 7, k = j & 127; v = ldf(w1, k * 128 + n, f32);
    } else if (i < R2_) {
        int j = i - R1_; int n = j >> 7, k = j & 127; v = ldf(w2, k * 128 + n, f32);
    } else if (i < R3_) {
        int j = i - R2_; int n = j >> 7, k = j & 127; v = ldf(wmu, k * 128 + n, f32);
    } else if (i < R4_) {
        int j = i - R3_; int n = j >> 7, k = j & 127; v = ldf(wvar, k * 128 + n, f32);
    } else if (i < R5_) {
        int j = i - R4_; int n = j >> 7, k = j & 127; v = ldf(wgat, k * 256 + n, f32);
    } else if (i < R6_) {
        int j = i - R5_; int n = j >> 8, k = j & 255; v = ldf(wdec, k * 128 + n, f32);
    } else {
        int j = i - R6_; int row = j / 96, k = j - row * 96;
        v = (k < DIN_) ? ldf(xin, row * DIN_ + k, f32) : 0.f;
    }
    dst[i] = __float2bfloat16(v);
}

// ---------------------------------------------------------------------------
// CSR build: XCD-region-partitioned histogram/scatter + 2-phase scan.
// ---------------------------------------------------------------------------
#define NBS ((NN + 255) / 256)       // 79 scan blocks
#define CHUNK 2048
#define NCH ((EE + CHUNK - 1) / CHUNK)   // 313 chunks

__global__ __launch_bounds__(256) void hist_kernel(const void* __restrict__ ei,
                                                   int* __restrict__ deg,
                                                   const int* __restrict__ flags)
{
    const int i64 = flags[1];
    int r = blockIdx.x & 7;
    int c = blockIdx.x >> 3;
    int base = c * CHUNK + threadIdx.x;
#pragma unroll
    for (int k = 0; k < CHUNK / 256; k++) {
        int e = base + k * 256;
        if (e < EE) {
            int d = i64 ? (int)((const long long*)ei)[EE + e] : ((const int*)ei)[EE + e];
            if (d / 2500 == r) atomicAdd(&deg[d], 1);
        }
    }
}

__global__ void scan1_kernel(const int* __restrict__ deg, int* __restrict__ bsum)
{
    int idx = blockIdx.x * 256 + threadIdx.x;
    int v = (idx < NN) ? deg[idx] : 0;
#pragma unroll
    for (int o = 32; o; o >>= 1) v += __shfl_down(v, o);
    __shared__ int s[4];
    if ((threadIdx.x & 63) == 0) s[threadIdx.x >> 6] = v;
    __syncthreads();
    if (threadIdx.x == 0) bsum[blockIdx.x] = s[0] + s[1] + s[2] + s[3];
}

// scan2 folded in: each block reduces bsum[0..blockIdx) itself (79 ints, trivial)
__global__ void scan23_kernel(const int* __restrict__ deg, const int* __restrict__ bsum,
                              int* __restrict__ off, int* __restrict__ cur)
{
    __shared__ int s[256];
    __shared__ int base_s;
    int t = threadIdx.x;
    int pv = (t < blockIdx.x) ? bsum[t] : 0;   // blockIdx.x <= 78 < 256
#pragma unroll
    for (int o = 32; o; o >>= 1) pv += __shfl_down(pv, o);
    if ((t & 63) == 0) s[t >> 6] = pv;
    __syncthreads();
    if (t == 0) {
        base_s = s[0] + s[1] + s[2] + s[3];
        if (blockIdx.x == 0) off[NN] = EE;
    }
    __syncthreads();
    int idx = blockIdx.x * 256 + t;
    int v = (idx < NN) ? deg[idx] : 0;
    s[t] = v;
    __syncthreads();
    for (int st = 1; st < 256; st <<= 1) {
        int u = (t >= st) ? s[t - st] : 0;
        __syncthreads();
        s[t] += u;
        __syncthreads();
    }
    if (idx < NN) { int o2 = base_s + s[t] - v; off[idx] = o2; cur[idx] = o2; }
}

__global__ __launch_bounds__(256) void scatter_kernel(const void* __restrict__ ei,
                                                      int* __restrict__ cur,
                                                      int* __restrict__ csr,
                                                      const int* __restrict__ flags)
{
    const int i64 = flags[1];
    int r = blockIdx.x & 7;
    int c = blockIdx.x >> 3;
    int base = c * CHUNK + threadIdx.x;
#pragma unroll
    for (int k = 0; k < CHUNK / 256; k++) {
        int e = base + k * 256;
        if (e < EE) {
            int d = i64 ? (int)((const long long*)ei)[EE + e] : ((const int*)ei)[EE + e];
            if (d / 2500 == r) {
                // src loaded only when region matches (saves 7/8 of src reads)
                int s = i64 ? (int)((const long long*)ei)[e] : ((const int*)ei)[e];
                int pos = atomicAdd(&cur[d], 1);
                csr[pos] = s;
            }
        }
    }
}

// ---------------------------------------------------------------------------
// MFMA GEMM (16x16x32 bf16): C[M,NC] = A @ W + bias.
// ---------------------------------------------------------------------------
template<int KP, int NC, int CG, int OUT_MODE>
__global__ __launch_bounds__(256) void mfma_gemm_kernel(
    const __hip_bfloat16* __restrict__ A,
    const __hip_bfloat16* __restrict__ WT,
    const void* __restrict__ bias,
    void* __restrict__ Cout, int out_off, const int* __restrict__ flags)
{
    const int f32 = flags[0];
    constexpr int MB = 16 * (4 / CG);
    constexpr int CT = NC / (16 * CG);
    int w = threadIdx.x >> 6, l = threadIdx.x & 63;
    int rt = w / CG, cg = w - rt * CG;
    int m0 = blockIdx.x * MB + rt * 16;
    int n0 = cg * (16 * CT);
    int l15 = l & 15, kq = (l >> 4) * 8;
    const __hip_bfloat16* arow = A + (size_t)(m0 + l15) * KP + kq;

    floatx4 acc[CT];
#pragma unroll
    for (int ct = 0; ct < CT; ct++) acc[ct] = (floatx4){0.f, 0.f, 0.f, 0.f};

    for (int kc = 0; kc < KP / 32; kc++) {
        short8 a = *(const short8*)(arow + kc * 32);
#pragma unroll
        for (int ct = 0; ct < CT; ct++) {
            const __hip_bfloat16* brow = WT + (size_t)(n0 + ct * 16 + l15) * KP + kq;
            short8 b = *(const short8*)(brow + kc * 32);
            acc[ct] = __builtin_amdgcn_mfma_f32_16x16x32_bf16(a, b, acc[ct], 0, 0, 0);
        }
    }

    int quad = l >> 4;
#pragma unroll
    for (int ct = 0; ct < CT; ct++) {
        int col = n0 + ct * 16 + l15;
        float bb = bias ? ldf(bias, col, f32) : 0.f;
#pragma unroll
        for (int r = 0; r < 4; r++) {
            int row = m0 + quad * 4 + r;
            float v = acc[ct][r] + bb;
            size_t o = (size_t)row * NC + col;
            if (OUT_MODE == 0)      ((float*)Cout)[o] = v;
            else if (OUT_MODE == 1) ((__hip_bfloat16*)Cout)[o] = __float2bfloat16(v);
            else                    stf(Cout, out_off + (int)o, v, f32);
        }
    }
}

// ---------------------------------------------------------------------------
// GAT GEMM with fused attention-score epilogue.
// KP=128, NC=256, CG=4 geometry: 16 rows/block, wave w covers cols [64w,64w+64),
// head = w>>1. AS/AD reduced over l15 via shfl_xor, combined across waves in LDS.
// Removes att_kernel + its 10 MB HH re-read per layer.
// ---------------------------------------------------------------------------
__global__ __launch_bounds__(256) void gemm_att_kernel(
    const __hip_bfloat16* __restrict__ A, const __hip_bfloat16* __restrict__ WT,
    __hip_bfloat16* __restrict__ HH,
    const void* __restrict__ attS, const void* __restrict__ attD,
    float* __restrict__ AS, float* __restrict__ AD, const int* __restrict__ flags)
{
    const int f32 = flags[0];
    int w = threadIdx.x >> 6, l = threadIdx.x & 63;
    int m0 = blockIdx.x * 16;
    int n0 = w * 64;
    int h  = w >> 1;
    int l15 = l & 15, quad = l >> 4, kq = quad * 8;
    const __hip_bfloat16* arow = A + (size_t)(m0 + l15) * 128 + kq;

    floatx4 acc[4];
#pragma unroll
    for (int ct = 0; ct < 4; ct++) acc[ct] = (floatx4){0.f, 0.f, 0.f, 0.f};

    for (int kc = 0; kc < 4; kc++) {
        short8 a = *(const short8*)(arow + kc * 32);
#pragma unroll
        for (int ct = 0; ct < 4; ct++) {
            const __hip_bfloat16* brow = WT + (size_t)(n0 + ct * 16 + l15) * 128 + kq;
            short8 b = *(const short8*)(brow + kc * 32);
            acc[ct] = __builtin_amdgcn_mfma_f32_16x16x32_bf16(a, b, acc[ct], 0, 0, 0);
        }
    }

    float spart[4] = {0.f, 0.f, 0.f, 0.f};
    float dpart[4] = {0.f, 0.f, 0.f, 0.f};
#pragma unroll
    for (int ct = 0; ct < 4; ct++) {
        int col = n0 + ct * 16 + l15;
        int cm  = col - 128 * h;
        float as_w = ldf(attS, h * CC + cm, f32);
        float ad_w = ldf(attD, h * CC + cm, f32);
#pragma unroll
        for (int r = 0; r < 4; r++) {
            float v = acc[ct][r];
            HH[(size_t)(m0 + quad * 4 + r) * 256 + col] = __float2bfloat16(v);
            spart[r] += v * as_w;
            dpart[r] += v * ad_w;
        }
    }
#pragma unroll
    for (int o = 1; o <= 8; o <<= 1) {
#pragma unroll
        for (int r = 0; r < 4; r++) {
            spart[r] += __shfl_xor(spart[r], o);
            dpart[r] += __shfl_xor(dpart[r], o);
        }
    }
    __shared__ float sS[4][16], sD[4][16];
    if (l15 == 0) {
#pragma unroll
        for (int r = 0; r < 4; r++) {
            sS[w][quad * 4 + r] = spart[r];
            sD[w][quad * 4 + r] = dpart[r];
        }
    }
    __syncthreads();
    int t = threadIdx.x;
    if (t < 32) {
        int row = t & 15, hh2 = t >> 4;
        AS[(m0 + row) * 2 + hh2] = sS[2 * hh2][row] + sS[2 * hh2 + 1][row];
        AD[(m0 + row) * 2 + hh2] = sD[2 * hh2][row] + sD[2 * hh2 + 1][row];
    }
}

// ---------------------------------------------------------------------------
// VAE-head GEMM with fused reparameterization epilogue.
// KP=128, NC=256 (mu|logvar), CG=4; acc staged through 16 KB LDS so each
// thread can pair mu[row,c] with logvar[row,c]. Removes z_kernel + 20 MB MULV
// round-trip; mu/logvar written to d_out at full fp32 (no bf16 round-trip).
// ---------------------------------------------------------------------------
__global__ __launch_bounds__(256) void gemm_z_kernel(
    const __hip_bfloat16* __restrict__ A, const __hip_bfloat16* __restrict__ WT,
    const void* __restrict__ eps, const void* __restrict__ b_mu, const void* __restrict__ b_var,
    __hip_bfloat16* __restrict__ Z, void* __restrict__ out, const int* __restrict__ flags)
{
    const int f32 = flags[0];
    __shared__ float zs[16][257];     // +1 pad breaks quad-stride bank conflicts
    int w = threadIdx.x >> 6, l = threadIdx.x & 63;
    int m0 = blockIdx.x * 16;
    int n0 = w * 64;
    int l15 = l & 15, quad = l >> 4, kq = quad * 8;
    const __hip_bfloat16* arow = A + (size_t)(m0 + l15) * 128 + kq;

    floatx4 acc[4];
#pragma unroll
    for (int ct = 0; ct < 4; ct++) acc[ct] = (floatx4){0.f, 0.f, 0.f, 0.f};

    for (int kc = 0; kc < 4; kc++) {
        short8 a = *(const short8*)(arow + kc * 32);
#pragma unroll
        for (int ct = 0; ct < 4; ct++) {
            const __hip_bfloat16* brow = WT + (size_t)(n0 + ct * 16 + l15) * 128 + kq;
            short8 b = *(const short8*)(brow + kc * 32);
            acc[ct] = __builtin_amdgcn_mfma_f32_16x16x32_bf16(a, b, acc[ct], 0, 0, 0);
        }
    }
#pragma unroll
    for (int ct = 0; ct < 4; ct++) {
#pragma unroll
        for (int r = 0; r < 4; r++)
            zs[quad * 4 + r][n0 + ct * 16 + l15] = acc[ct][r];
    }
    __syncthreads();
    int t = threadIdx.x;
    const int NB2 = NN * CC;
#pragma unroll
    for (int k = 0; k < 8; k++) {
        int idx = k * 256 + t;
        int row = idx >> 7, c = idx & 127;
        float mu = zs[row][c]       + ldf(b_mu,  c, f32);
        float lv = zs[row][128 + c] + ldf(b_var, c, f32);
        int gi = (m0 + row) * 128 + c;
        float z = ldf(eps, gi, f32) * expf(0.5f * lv) + mu;
        Z[gi] = __float2bfloat16(z);
        stf(out, gi, z, f32);                 // zin
        stf(out, 2 * NB2 + gi, mu, f32);      // mu
        stf(out, 3 * NB2 + gi, lv, f32);      // logvar
    }
}

// ---------------------------------------------------------------------------
// Fused GAT softmax-stats + aggregation: one 64-lane wave per dst node.
// Lanes split by head for the 2-pass (max,sum) over AS (L2-hot, 160 KB);
// aggregation pass recomputes alpha inline (~6 VALU/edge, AS loads broadcast).
// Removes ALPHA/SALPHA materialization (21 MB/iter) + one dispatch per layer;
// wave now covers a single dst -> no inter-half edge-loop divergence.
// ---------------------------------------------------------------------------
__global__ __launch_bounds__(256) void gat_fused_kernel(
    const uint2* __restrict__ HH2,
    const float* __restrict__ AS, const float* __restrict__ AD,
    const int* __restrict__ off, const int* __restrict__ csr,
    const void* __restrict__ b_gat, uint2* __restrict__ OUT2,
    const int* __restrict__ flags)
{
    const int f32 = flags[0];
    int d = (blockIdx.x * blockDim.x + threadIdx.x) >> 6;
    int l = threadIdx.x & 63;
    if (d >= NN) return;
    int h = l >> 5, j = l & 31;
    int b = off[d], e = off[d + 1];
    float adh = AD[d * 2 + h];
    float self_l = leaky02(AS[d * 2 + h] + adh);

    // pass 1: max
    float m = self_l;
    for (int i = b + j; i < e; i += 32)
        m = fmaxf(m, leaky02(AS[csr[i] * 2 + h] + adh));
#pragma unroll
    for (int o = 16; o; o >>= 1) m = fmaxf(m, __shfl_xor(m, o));   // stays within half

    // pass 2: sum
    float sum = (j == 0) ? expf(self_l - m) : 0.f;
    for (int i = b + j; i < e; i += 32)
        sum += expf(leaky02(AS[csr[i] * 2 + h] + adh) - m);
#pragma unroll
    for (int o = 16; o; o >>= 1) sum += __shfl_xor(sum, o);
    float inv = 1.f / sum;

    // aggregation: lane l covers cols 4l..4l+3 (uint2 = 4 bf16); head = l>>5 consistent
    float a0 = expf(self_l - m) * inv;
    uint2 wv = HH2[(size_t)d * 64 + l];
    float4 p = bf4(wv.x, wv.y);
    float4 acc = make_float4(a0 * p.x, a0 * p.y, a0 * p.z, a0 * p.w);
    int i = b;
    for (; i + 4 <= e; i += 4) {
        int s0 = csr[i], s1 = csr[i + 1], s2 = csr[i + 2], s3 = csr[i + 3];
        float a1 = expf(leaky02(AS[s0 * 2 + h] + adh) - m) * inv;
        float a2 = expf(leaky02(AS[s1 * 2 + h] + adh) - m) * inv;
        float a3 = expf(leaky02(AS[s2 * 2 + h] + adh) - m) * inv;
        float a4 = expf(leaky02(AS[s3 * 2 + h] + adh) - m) * inv;
        uint2 w0 = HH2[(size_t)s0 * 64 + l];
        uint2 w1 = HH2[(size_t)s1 * 64 + l];
        uint2 w2 = HH2[(size_t)s2 * 64 + l];
        uint2 w3 = HH2[(size_t)s3 * 64 + l];
        float4 f;
        f = bf4(w0.x, w0.y); acc.x += a1 * f.x; acc.y += a1 * f.y; acc.z += a1 * f.z; acc.w += a1 * f.w;
        f = bf4(w1.x, w1.y); acc.x += a2 * f.x; acc.y += a2 * f.y; acc.z += a2 * f.z; acc.w += a2 * f.w;
        f = bf4(w2.x, w2.y); acc.x += a3 * f.x; acc.y += a3 * f.y; acc.z += a3 * f.z; acc.w += a3 * f.w;
        f = bf4(w3.x, w3.y); acc.x += a4 * f.x; acc.y += a4 * f.y; acc.z += a4 * f.z; acc.w += a4 * f.w;
    }
    for (; i < e; i++) {
        int s = csr[i];
        float al = expf(leaky02(AS[s * 2 + h] + adh) - m) * inv;
        uint2 wq = HH2[(size_t)s * 64 + l];
        float4 f = bf4(wq.x, wq.y);
        acc.x += al * f.x; acc.y += al * f.y; acc.z += al * f.z; acc.w += al * f.w;
    }
    int c0 = 4 * l;
    acc.x += ldf(b_gat, c0 + 0, f32); acc.y += ldf(b_gat, c0 + 1, f32);
    acc.z += ldf(b_gat, c0 + 2, f32); acc.w += ldf(b_gat, c0 + 3, f32);
    OUT2[(size_t)d * 64 + l] = f4bf(acc);
}

// ---------------------------------------------------------------------------
// BatchNorm (training) on bf16 Y — single reduce kernel, atomicAdd into
// pre-zeroed per-stage sums[256] (0..127 sum, 128..255 sumsq).
// 128 blocks x 256 atomics = 32K fp32 atomics -> negligible contention.
// ---------------------------------------------------------------------------
#define BNB 128

__global__ __launch_bounds__(256) void bn_part_kernel(const unsigned* __restrict__ Y1,
                                                      float* __restrict__ sums)
{
    int c2 = threadIdx.x & 63;          // channel pair
    int rg = threadIdx.x >> 6;          // 4 row groups / block
    float s0 = 0.f, q0 = 0.f, s1 = 0.f, q1 = 0.f;
    for (int r = blockIdx.x * 4 + rg; r < NN; r += BNB * 4) {
        float2 v = bfp(Y1[r * 64 + c2]);
        s0 += v.x; q0 += v.x * v.x;
        s1 += v.y; q1 += v.y * v.y;
    }
    __shared__ float rs[4][128], rq[4][128];
    rs[rg][2 * c2] = s0; rs[rg][2 * c2 + 1] = s1;
    rq[rg][2 * c2] = q0; rq[rg][2 * c2 + 1] = q1;
    __syncthreads();
    int c = threadIdx.x;
    if (c < 128) {
        atomicAdd(&sums[c], rs[0][c] + rs[1][c] + rs[2][c] + rs[3][c]);
    } else {
        int ch = c - 128;
        atomicAdd(&sums[128 + ch], rq[0][ch] + rq[1][ch] + rq[2][ch] + rq[3][ch]);
    }
}

__global__ void bn_relu_kernel(const unsigned* __restrict__ Y1, unsigned* __restrict__ X1,
                               const float* __restrict__ sums, const float* __restrict__ sumsq,
                               const void* __restrict__ g, const void* __restrict__ be,
                               const int* __restrict__ flags)
{
    const int f32 = flags[0];
    int idx = blockIdx.x * blockDim.x + threadIdx.x;
    if (idx >= NN * 64) return;
    int c2 = idx & 63;
    int c0 = 2 * c2, c1 = c0 + 1;
    float2 v = bfp(Y1[idx]);
    float mean0 = sums[c0] * (1.f / NN), mean1 = sums[c1] * (1.f / NN);
    float var0  = sumsq[c0] * (1.f / NN) - mean0 * mean0;
    float var1  = sumsq[c1] * (1.f / NN) - mean1 * mean1;
    float o0 = (v.x - mean0) * rsqrtf(fmaxf(var0, 0.f) + BN_EPS) * ldf(g, c0, f32) + ldf(be, c0, f32);
    float o1 = (v.y - mean1) * rsqrtf(fmaxf(var1, 0.f) + BN_EPS) * ldf(g, c1, f32) + ldf(be, c1, f32);
    X1[idx] = f2bf(make_float2(o0 > 0.f ? o0 : 0.f, o1 > 0.f ? o1 : 0.f));
}

// ---------------------------------------------------------------------------
// GIN: H[d] = X[d] + sum_{s in N(d)} X[s]
// Half-wave per dst: 32 lanes x uint2 (8 B) = full 256 B bf16 row. 4-deep.
// (8-deep regressed: VGPR 32->56, occupancy 55->30% — r12 post-mortem)
// ---------------------------------------------------------------------------
__global__ __launch_bounds__(256) void gin_gather_kernel(
    const uint2* __restrict__ X2, uint2* __restrict__ H2,
    const int* __restrict__ off, const int* __restrict__ csr)
{
    int hw = (blockIdx.x * blockDim.x + threadIdx.x) >> 5;
    int l5 = threadIdx.x & 31;
    if (hw >= NN) return;
    int d = hw;
    uint2 w0 = X2[(size_t)d * 32 + l5];
    float4 acc = bf4(w0.x, w0.y);
    int b = off[d], e = off[d + 1];
    int i = b;
    for (; i + 4 <= e; i += 4) {
        int s0 = csr[i], s1 = csr[i + 1], s2 = csr[i + 2], s3 = csr[i + 3];
        uint2 a0 = X2[(size_t)s0 * 32 + l5];
        uint2 a1 = X2[(size_t)s1 * 32 + l5];
        uint2 a2 = X2[(size_t)s2 * 32 + l5];
        uint2 a3 = X2[(size_t)s3 * 32 + l5];
        float4 f0 = bf4(a0.x, a0.y), f1 = bf4(a1.x, a1.y);
        float4 f2 = bf4(a2.x, a2.y), f3 = bf4(a3.x, a3.y);
        acc.x += f0.x + f1.x + f2.x + f3.x;
        acc.y += f0.y + f1.y + f2.y + f3.y;
        acc.z += f0.z + f1.z + f2.z + f3.z;
        acc.w += f0.w + f1.w + f2.w + f3.w;
    }
    for (; i < e; i++) {
        uint2 a = X2[(size_t)csr[i] * 32 + l5];
        float4 f = bf4(a.x, a.y);
        acc.x += f.x; acc.y += f.y; acc.z += f.z; acc.w += f.w;
    }
    H2[(size_t)d * 32 + l5] = f4bf(acc);
}

// ---------------------------------------------------------------------------
extern "C" void kernel_launch(void* const* d_in, const int* in_sizes, int n_in,
                              void* d_out, int out_size, void* d_ws, size_t ws_size,
                              hipStream_t stream)
{
    const void* xin    = d_in[0];
    const void* ei     = d_in[1];
    const void* eps    = d_in[2];
    const void* W_emb  = d_in[3];
    const void* b_emb  = d_in[4];
    const void* g_emb  = d_in[5];
    const void* be_emb = d_in[6];
    const void* W1     = d_in[7];
    const void* b1     = d_in[8];
    const void* g1     = d_in[9];
    const void* be1    = d_in[10];
    const void* W2     = d_in[11];
    const void* b2     = d_in[12];
    const void* W_mu   = d_in[13];
    const void* b_mu   = d_in[14];
    const void* W_var  = d_in[15];
    const void* b_var  = d_in[16];
    const void* W_gat  = d_in[17];
    const void* attS   = d_in[18];
    const void* attD   = d_in[19];
    const void* b_gat  = d_in[20];
    const void* W_dec  = d_in[21];
    const void* b_dec  = d_in[22];

    // workspace layout
    float* ws = (float*)d_ws;
    const size_t NB = (size_t)NN * CC;       // 2,560,000
    float* B0 = ws;                          // bf16 HH (N x 256)
    float* B1 = ws + 1 * NB;                 // bf16 Y | bf16 OUT (N x 256)
    float* B2 = ws + 2 * NB;                 // bf16 Xbf | Hbf
    float* B3 = ws + 3 * NB;                 // bf16 Zbf | Zobf
    __hip_bfloat16* Xbf   = (__hip_bfloat16*)B2;       // N x 128
    __hip_bfloat16* Hbf   = Xbf + NB;                  // N x 128
    __hip_bfloat16* Zbf   = (__hip_bfloat16*)B3;       // N x 128
    __hip_bfloat16* Zobf  = Zbf + NB;                  // N x 128
    __hip_bfloat16* HHbf  = (__hip_bfloat16*)B0;       // N x 256
    __hip_bfloat16* OUTbf = (__hip_bfloat16*)B1;       // N x 256
    __hip_bfloat16* Ybf   = (__hip_bfloat16*)B1;       // N x 128 (BN input)
    float* TAIL = ws + 4 * NB;
    float* AS      = TAIL;                        // 40000
    float* AD      = TAIL + 40000;                // 40000
    int*   FLAGS   = (int*)(TAIL + 80000);        // 16
    int*   BSUM    = FLAGS + 16;                  // 128
    float* SUMSALL = (float*)(BSUM + 128);        // 3 x 256 (zeroed)
    int*   DEG     = (int*)(SUMSALL + 768);       // 20000 (zeroed, contiguous after SUMSALL)
    int*   OFF     = DEG + 20000;                 // 20008 (padded)
    int*   CUR     = OFF + 20008;                 // 20000
    int*   CSR     = CUR + 20000;                 // 640000
    __hip_bfloat16* WTB = (__hip_bfloat16*)(CSR + 640000);  // 143360 bf16
    __hip_bfloat16* WTemb = WTB;
    __hip_bfloat16* WT1   = WTB + R0_;
    __hip_bfloat16* WT2   = WTB + R1_;
    __hip_bfloat16* WTmuv = WTB + R2_;       // mu|var contiguous -> NC=256
    __hip_bfloat16* WTgat = WTB + R4_;
    __hip_bfloat16* WTdec = WTB + R5_;
    __hip_bfloat16* Xin   = WTB + R6_;       // NN x 96 bf16

    detect_kernel<<<1, 256, 0, stream>>>((const unsigned int*)xin,
                                         (const unsigned int*)ei, FLAGS);

    // -------- merged weight transpose + node-feature conversion --------
    cvt_all_kernel<<<(TCVT + 255) / 256, 256, 0, stream>>>(
        W_emb, W1, W2, W_mu, W_var, W_gat, W_dec, xin, WTB, FLAGS);

    // -------- memset: BN sums (3 x 256) + DEG, contiguous --------
    hipMemsetAsync(SUMSALL, 0, (768 + 20000) * sizeof(int), stream);

    // -------- CSR build (sorted by destination, XCD-region partitioned) ------
    hist_kernel<<<NCH * 8, 256, 0, stream>>>(ei, DEG, FLAGS);
    scan1_kernel<<<NBS, 256, 0, stream>>>(DEG, BSUM);
    scan23_kernel<<<NBS, 256, 0, stream>>>(DEG, BSUM, OFF, CUR);
    scatter_kernel<<<NCH * 8, 256, 0, stream>>>(ei, CUR, CSR, FLAGS);

    // -------- Stage A: atom embedding = relu(BN(x @ W_emb + b_emb)) -> Xbf ----
    mfma_gemm_kernel<96, 128, 2, 1><<<NN / 32, 256, 0, stream>>>(
        Xin, WTemb, b_emb, Ybf, 0, FLAGS);
    bn_part_kernel<<<BNB, 256, 0, stream>>>((const unsigned*)Ybf, SUMSALL);
    bn_relu_kernel<<<(NN * 64) / 256, 256, 0, stream>>>(
        (const unsigned*)Ybf, (unsigned*)Xbf, SUMSALL, SUMSALL + 128, g_emb, be_emb, FLAGS);

    // -------- Stage B: GIN x2: x = W2( relu(BN(W1(x+agg))) ) --------
    for (int t = 0; t < 2; t++) {
        float* SUMS_T = SUMSALL + 256 * (1 + t);
        gin_gather_kernel<<<NN / 8, 256, 0, stream>>>(
            (const uint2*)Xbf, (uint2*)Hbf, OFF, CSR);
        mfma_gemm_kernel<128, 128, 2, 1><<<NN / 32, 256, 0, stream>>>(
            Hbf, WT1, b1, Ybf, 0, FLAGS);
        bn_part_kernel<<<BNB, 256, 0, stream>>>((const unsigned*)Ybf, SUMS_T);
        bn_relu_kernel<<<(NN * 64) / 256, 256, 0, stream>>>(
            (const unsigned*)Ybf, (unsigned*)Hbf, SUMS_T, SUMS_T + 128, g1, be1, FLAGS);
        mfma_gemm_kernel<128, 128, 2, 1><<<NN / 32, 256, 0, stream>>>(
            Hbf, WT2, b2, Xbf, 0, FLAGS);
    }

    // -------- Stage C: VAE heads + reparameterization, fused --------
    gemm_z_kernel<<<NN / 16, 256, 0, stream>>>(
        Xbf, WTmuv, eps, b_mu, b_var, Zbf, d_out, FLAGS);

    // -------- Stage D: GAT x2; attention fused into GEMM epilogue;
    //          softmax-stats fused into aggregation --------
    const __hip_bfloat16* zc = Zbf;
    for (int t = 0; t < 2; t++) {
        gemm_att_kernel<<<NN / 16, 256, 0, stream>>>(
            zc, WTgat, HHbf, attS, attD, AS, AD, FLAGS);
        gat_fused_kernel<<<(NN * 64) / 256, 256, 0, stream>>>(
            (const uint2*)HHbf, AS, AD, OFF, CSR, b_gat, (uint2*)OUTbf, FLAGS);
        if (t == 0) {
            mfma_gemm_kernel<256, 128, 2, 1><<<NN / 32, 256, 0, stream>>>(
                OUTbf, WTdec, b_dec, Zobf, 0, FLAGS);
            zc = Zobf;
        } else {
            mfma_gemm_kernel<256, 128, 2, 2><<<NN / 32, 256, 0, stream>>>(
                OUTbf, WTdec, b_dec, d_out, NN * CC, FLAGS);
        }
    }
}